// Round 6
// baseline (94.847 us; speedup 1.0000x reference)
//
#include <hip/hip_runtime.h>
#include <hip/hip_bf16.h>
#include <hip/hip_cooperative_groups.h>
#include <math.h>

namespace cg = cooperative_groups;

// Problem: x (64, 2, 512, 512) f32. x0 = x[:,0] -> (64,512,512).
// n[v] = sqrt(sum_{b,f} x0[b,v,f]^2)
// out[b,i,j] = (sum_f x0[b,i,f]*x0[b,j,f]) / (n[i]*n[j])

#define BATCH 64
#define VDIM 512
#define FDIM 512
#define XBS (2 * VDIM * FDIM)      // x batch stride in floats (T=2)
#define OBS (VDIM * VDIM)          // out batch stride in floats

typedef __bf16 bf16x8 __attribute__((ext_vector_type(8)));
typedef __bf16 bf16x4 __attribute__((ext_vector_type(4)));
typedef float f32x4 __attribute__((ext_vector_type(4)));

// ws layout: [0, 33554432): bf16 x0 copy; then f32 nsq[512]
#define NSQ_OFF 33554432

#define GLL16(g, l)                                                          \
    __builtin_amdgcn_global_load_lds(                                        \
        (const __attribute__((address_space(1))) void*)(g),                  \
        (__attribute__((address_space(3))) void*)(l), 16, 0, 0)

// One cooperative kernel: 256 blocks x 512 threads (1 block/CU).
// Phase A: block (batch,q) converts 128 rows f32->bf16 ws + accumulates nsq[v].
// grid.sync()
// Phase B: block (batch,tile) computes a 256^2 gram tile from ws (L2-local),
//          dbuf LDS + counted vmcnt pipeline, scales by rsqrt(nsq) in epilogue.
__global__ __launch_bounds__(512, 2) void fused_kernel(const float* __restrict__ x,
                                                       __bf16* __restrict__ ws,
                                                       float* __restrict__ nsq,
                                                       float* __restrict__ out) {
    __shared__ __bf16 As[2][16384];   // 2 x 32 KB
    __shared__ __bf16 Bs[2][16384];   // 2 x 32 KB
    __shared__ float nsq_l[128];

    const int bid = blockIdx.x;
    const int L = (bid & 7) * 32 + (bid >> 3);   // chunked XCD map (256 % 8 == 0)
    const int tid = threadIdx.x;
    const int lane = tid & 63;
    const int wave = tid >> 6;       // 0..7

    // ================= Phase A =================
    {
        const int b = L >> 2;
        const int q = L & 3;
        if (tid < 128) nsq_l[tid] = 0.f;
        __syncthreads();
        // contiguous 256 KB slab: x0[b, 128q .. 128q+128, :]
        const float4* src = (const float4*)(x + (size_t)b * XBS + (size_t)q * 128 * FDIM);
        bf16x4* dst = (bf16x4*)(ws + (size_t)b * (VDIM * FDIM) + (size_t)q * 128 * FDIM);
        const int row_w = wave >> 1;             // all 64 lanes of a wave share a row
        #pragma unroll 4
        for (int i = 0; i < 32; ++i) {
            int c = i * 512 + tid;
            float4 d = src[c];
            bf16x4 p;
            p[0] = (__bf16)d.x; p[1] = (__bf16)d.y; p[2] = (__bf16)d.z; p[3] = (__bf16)d.w;
            dst[c] = p;
            float s = d.x * d.x + d.y * d.y + d.z * d.z + d.w * d.w;
            #pragma unroll
            for (int off = 32; off > 0; off >>= 1) s += __shfl_down(s, off, 64);
            if (lane == 0) atomicAdd(&nsq_l[i * 4 + row_w], s);
        }
        __syncthreads();
        if (tid < 128) atomicAdd(&nsq[q * 128 + tid], nsq_l[tid]);
    }

    cg::this_grid().sync();

    // ================= Phase B =================
    const int batch = L >> 2;
    const int tile = L & 3;
    const int tr = tile >> 1;
    const int tc = tile & 1;
    const __bf16* wsb = ws + (size_t)batch * (VDIM * FDIM);
    const int wr = wave >> 2;        // 0..1
    const int wc = wave & 3;         // 0..3

    // staging: chunk c = j*512 + tid, j<4: row = c>>3 in [0,256), cc = c&7
    // LDS chunk (row,cc) holds global chunk (row, cc ^ (row&7))  [both-sides XOR]
    const int r0 = tid >> 3;
    const int cc = tid & 7;
    const __bf16* gA[4];
    const __bf16* gB[4];
    int lo[4];
    #pragma unroll
    for (int j = 0; j < 4; ++j) {
        int row = j * 64 + r0;
        int cs = cc ^ (row & 7);
        gA[j] = wsb + (size_t)(tr * 256 + row) * FDIM + cs * 8;
        gB[j] = wsb + (size_t)(tc * 256 + row) * FDIM + cs * 8;
        lo[j] = (j * 512 + tid) * 8;
    }

    auto stage = [&](int kt) {
        const int nb = kt & 1;
        #pragma unroll
        for (int j = 0; j < 4; ++j) GLL16(gA[j] + kt * 64, &As[nb][lo[j]]);
        #pragma unroll
        for (int j = 0; j < 4; ++j) GLL16(gB[j] + kt * 64, &Bs[nb][lo[j]]);
    };

    // fragment LDS byte offsets: element (r, k=ks*32+(lane>>4)*8) at chunk
    // g = ks*4+(lane>>4), swizzled g^(r&7); r&7 == lane&7; ks toggles byte ^64.
    const int gs0 = (lane >> 4) ^ (lane & 7);
    const int abase = (wr * 128 + (lane & 15)) * 128 + gs0 * 16;
    const int bbase = (wc * 64 + (lane & 15)) * 128 + gs0 * 16;

    f32x4 acc[8][4];
    #pragma unroll
    for (int m = 0; m < 8; ++m)
        #pragma unroll
        for (int n = 0; n < 4; ++n)
            acc[m][n] = (f32x4){0.f, 0.f, 0.f, 0.f};

    stage(0);
    #pragma unroll
    for (int kt = 0; kt < 8; ++kt) {
        if (kt < 7) {
            stage(kt + 1);
            asm volatile("s_waitcnt vmcnt(8)" ::: "memory");   // kt's 8 loads landed
        } else {
            asm volatile("s_waitcnt vmcnt(0)" ::: "memory");
        }
        __builtin_amdgcn_s_barrier();

        const char* Ab = (const char*)&As[kt & 1][0];
        const char* Bb = (const char*)&Bs[kt & 1][0];
        #pragma unroll
        for (int ks = 0; ks < 2; ++ks) {
            bf16x8 af[8], bfr[4];
            #pragma unroll
            for (int m = 0; m < 8; ++m)
                af[m] = *(const bf16x8*)(Ab + ((abase + m * 2048) ^ (ks * 64)));
            #pragma unroll
            for (int n = 0; n < 4; ++n)
                bfr[n] = *(const bf16x8*)(Bb + ((bbase + n * 2048) ^ (ks * 64)));
            #pragma unroll
            for (int m = 0; m < 8; ++m)
                #pragma unroll
                for (int n = 0; n < 4; ++n)
                    acc[m][n] = __builtin_amdgcn_mfma_f32_16x16x32_bf16(af[m], bfr[n], acc[m][n], 0, 0, 0);
        }
        asm volatile("s_waitcnt lgkmcnt(0)" ::: "memory");  // my ds_reads retired
        __builtin_amdgcn_s_barrier();   // safe to overwrite buf (kt&1)
    }

    // ---- epilogue: scale by rsqrt(nsq[i])*rsqrt(nsq[j]), store ----
    const int rowbase = tr * 256 + wr * 128;
    const int colbase = tc * 256 + wc * 64;
    float* ob = out + (size_t)batch * OBS;

    float si[32];
    #pragma unroll
    for (int m = 0; m < 8; ++m)
        #pragma unroll
        for (int q = 0; q < 4; ++q)
            si[m * 4 + q] = rsqrtf(nsq[rowbase + m * 16 + (lane >> 4) * 4 + q]);

    #pragma unroll
    for (int n = 0; n < 4; ++n) {
        int j = colbase + n * 16 + (lane & 15);
        float sj = rsqrtf(nsq[j]);
        #pragma unroll
        for (int m = 0; m < 8; ++m) {
            #pragma unroll
            for (int q = 0; q < 4; ++q) {
                int i = rowbase + m * 16 + (lane >> 4) * 4 + q;
                ob[(size_t)i * VDIM + j] = acc[m][n][q] * si[m * 4 + q] * sj;
            }
        }
    }
}

extern "C" void kernel_launch(void* const* d_in, const int* in_sizes, int n_in,
                              void* d_out, int out_size, void* d_ws, size_t ws_size,
                              hipStream_t stream) {
    const float* x = (const float*)d_in[0];
    float* out = (float*)d_out;
    __bf16* ws = (__bf16*)d_ws;
    float* nsq = (float*)((char*)d_ws + NSQ_OFF);

    // nsq accumulates via atomics every call; ws is not re-poisoned between
    // replays, so zero nsq deterministically each launch (capture-legal).
    hipMemsetAsync(nsq, 0, VDIM * sizeof(float), stream);

    void* args[] = {(void*)&x, (void*)&ws, (void*)&nsq, (void*)&out};
    hipLaunchCooperativeKernel((const void*)fused_kernel, dim3(256), dim3(512),
                               args, 0, stream);
}

// Round 7
// 69.545 us; speedup vs baseline: 1.3638x; 1.3638x over previous
//
#include <hip/hip_runtime.h>
#include <hip/hip_bf16.h>
#include <math.h>

// Problem: x (64, 2, 512, 512) f32. x0 = x[:,0] -> (64,512,512).
// n[v] = sqrt(sum_{b,f} x0[b,v,f]^2)
// out[b,i,j] = (sum_f x0[b,i,f]*x0[b,j,f]) / (n[i]*n[j])

#define BATCH 64
#define VDIM 512
#define FDIM 512
#define XBS (2 * VDIM * FDIM)      // x batch stride in floats (T=2)
#define OBS (VDIM * VDIM)          // out batch stride in floats

typedef __bf16 bf16x8 __attribute__((ext_vector_type(8)));
typedef __bf16 bf16x4 __attribute__((ext_vector_type(4)));
typedef float f32x4 __attribute__((ext_vector_type(4)));

#define BM 128
#define BK 64                      // bf16 elems per K-step

// ws layout: [0, 33554432): bf16 x0 copy (64*512*512); then f32 inv_n[512]
#define INVN_OFF 33554432

// global -> LDS direct copy, 16B per lane (dest is wave-uniform base + lane*16)
#define GLL16(g, l)                                                          \
    __builtin_amdgcn_global_load_lds(                                        \
        (const __attribute__((address_space(1))) void*)(g),                  \
        (__attribute__((address_space(3))) void*)(l), 16, 0, 0)

// ---------------- fused norm + bf16-convert kernel: one block per v ----------------
__global__ __launch_bounds__(512) void cvt_norm_kernel(const float* __restrict__ x,
                                                       __bf16* __restrict__ xb,
                                                       float* __restrict__ inv_n) {
    const int v = blockIdx.x;
    const int tid = threadIdx.x;
    float s = 0.f;
    const f32x4* xf4 = (const f32x4*)x;
    // 64 batches x 128 float4 per (b, v) row; x is use-once -> nt loads,
    // ws is consumed on other XCDs via L3 -> nt stores (don't pollute L2)
    for (int c = tid; c < 8192; c += 512) {
        int b = c >> 7;
        int f4 = c & 127;
        f32x4 d = __builtin_nontemporal_load(
            &xf4[(size_t)b * (XBS / 4) + (size_t)v * (FDIM / 4) + f4]);
        s += d[0] * d[0] + d[1] * d[1] + d[2] * d[2] + d[3] * d[3];
        bf16x4 p;
        p[0] = (__bf16)d[0]; p[1] = (__bf16)d[1]; p[2] = (__bf16)d[2]; p[3] = (__bf16)d[3];
        __builtin_nontemporal_store(
            p, (bf16x4*)&xb[(size_t)b * (VDIM * FDIM) + (size_t)v * FDIM + f4 * 4]);
    }
    #pragma unroll
    for (int off = 32; off > 0; off >>= 1) s += __shfl_down(s, off, 64);
    __shared__ float partial[8];
    if ((tid & 63) == 0) partial[tid >> 6] = s;
    __syncthreads();
    if (tid == 0) {
        float t = 0.f;
        #pragma unroll
        for (int w = 0; w < 8; ++w) t += partial[w];
        inv_n[v] = 1.0f / sqrtf(t);
    }
}

// ---------------- gram kernel: bf16 global_load_lds + swizzled LDS ----------------
__global__ __launch_bounds__(256, 3) void gram_kernel(const __bf16* __restrict__ xb,
                                                      const float* __restrict__ inv_n,
                                                      float* __restrict__ out) {
    __shared__ __bf16 As[BM * BK];   // 16 KB, linear [128][64] (+XOR swizzle via src)
    __shared__ __bf16 Bs[BM * BK];

    // 64 batches x 16 tiles = 1024 blocks
    // XCD chunked swizzle: 1024 / 8 = 128 contiguous logical wgs per XCD (8 batches)
    const int bid = blockIdx.x;
    const int wg = (bid & 7) * 128 + (bid >> 3);
    const int batch = wg >> 4;
    const int tile = wg & 15;
    const int ti = tile >> 2;
    const int tj = tile & 3;

    const __bf16* xbb = xb + (size_t)batch * (VDIM * FDIM);
    const int tid = threadIdx.x;
    const int lane = tid & 63;
    const int wave = tid >> 6;     // 0..3
    const int wr = wave >> 1;      // 0..1
    const int wc = wave & 1;       // 0..1

    // ---- staging addresses (constant per thread; only kk advances) ----
    // chunk c = it*256 + tid in [0,1024): row = c>>3, cc = c&7
    // LDS chunk (row,cc) holds global 16B-chunk (row, cc ^ (row&7))  [both-sides XOR]
    const __bf16* gA[4];
    const __bf16* gB[4];
    __bf16* la[4];
    __bf16* lb[4];
    #pragma unroll
    for (int it = 0; it < 4; ++it) {
        int c = it * 256 + tid;
        int row = c >> 3;
        int cs = (c & 7) ^ (row & 7);
        gA[it] = xbb + (size_t)(ti * BM + row) * FDIM + cs * 8;
        gB[it] = xbb + (size_t)(tj * BM + row) * FDIM + cs * 8;
        la[it] = &As[c * 8];
        lb[it] = &Bs[c * 8];
    }

    // ---- fragment LDS byte offsets (constant per lane) ----
    // element (r, k=ks*32+(lane>>4)*8) lives at LDS chunk (r, (ks*4+(lane>>4)) ^ (r&7))
    int offA[2][4], offB[2][4];
    #pragma unroll
    for (int ks = 0; ks < 2; ++ks) {
        #pragma unroll
        for (int m = 0; m < 4; ++m) {
            int rA = wr * 64 + m * 16 + (lane & 15);
            int rB = wc * 64 + m * 16 + (lane & 15);
            int gch = ks * 4 + (lane >> 4);
            offA[ks][m] = rA * (BK * 2) + ((gch ^ (rA & 7)) * 16);
            offB[ks][m] = rB * (BK * 2) + ((gch ^ (rB & 7)) * 16);
        }
    }

    f32x4 acc[4][4];
    #pragma unroll
    for (int m = 0; m < 4; ++m)
        #pragma unroll
        for (int n = 0; n < 4; ++n)
            acc[m][n] = (f32x4){0.f, 0.f, 0.f, 0.f};

    for (int kk = 0; kk < FDIM; kk += BK) {
        #pragma unroll
        for (int it = 0; it < 4; ++it) {
            GLL16(gA[it] + kk, la[it]);
            GLL16(gB[it] + kk, lb[it]);
        }
        __syncthreads();   // compiler emits vmcnt(0) drain before barrier

        #pragma unroll
        for (int ks = 0; ks < 2; ++ks) {
            bf16x8 af[4], bfr[4];
            #pragma unroll
            for (int m = 0; m < 4; ++m) {
                af[m]  = *(const bf16x8*)((const char*)As + offA[ks][m]);
                bfr[m] = *(const bf16x8*)((const char*)Bs + offB[ks][m]);
            }
            #pragma unroll
            for (int m = 0; m < 4; ++m)
                #pragma unroll
                for (int n = 0; n < 4; ++n)
                    acc[m][n] = __builtin_amdgcn_mfma_f32_16x16x32_bf16(af[m], bfr[n], acc[m][n], 0, 0, 0);
        }
        __syncthreads();
    }

    // ---- epilogue: scale by inv_n[i]*inv_n[j], nontemporal store (keep L2 for ws) ----
    const int rowbase = ti * BM + wr * 64;
    const int colbase = tj * BM + wc * 64;
    float* ob = out + (size_t)batch * OBS;

    float si[16];
    #pragma unroll
    for (int m = 0; m < 4; ++m)
        #pragma unroll
        for (int q = 0; q < 4; ++q)
            si[m * 4 + q] = inv_n[rowbase + m * 16 + (lane >> 4) * 4 + q];

    #pragma unroll
    for (int n = 0; n < 4; ++n) {
        int j = colbase + n * 16 + (lane & 15);
        float sj = inv_n[j];
        #pragma unroll
        for (int m = 0; m < 4; ++m) {
            #pragma unroll
            for (int q = 0; q < 4; ++q) {
                int i = rowbase + m * 16 + (lane >> 4) * 4 + q;
                __builtin_nontemporal_store(acc[m][n][q] * si[m * 4 + q] * sj,
                                            &ob[(size_t)i * VDIM + j]);
            }
        }
    }
}

extern "C" void kernel_launch(void* const* d_in, const int* in_sizes, int n_in,
                              void* d_out, int out_size, void* d_ws, size_t ws_size,
                              hipStream_t stream) {
    const float* x = (const float*)d_in[0];
    float* out = (float*)d_out;
    __bf16* xbf = (__bf16*)d_ws;
    float* inv_n = (float*)((char*)d_ws + INVN_OFF);

    cvt_norm_kernel<<<VDIM, 512, 0, stream>>>(x, xbf, inv_n);
    gram_kernel<<<BATCH * 16, 256, 0, stream>>>(xbf, inv_n, out);
}

// Round 8
// 51.231 us; speedup vs baseline: 1.8514x; 1.3575x over previous
//
#include <hip/hip_runtime.h>
#include <hip/hip_bf16.h>
#include <math.h>

// Problem: x (64, 2, 512, 512) f32. x0 = x[:,0] -> (64,512,512).
// n[v] = sqrt(sum_{b,f} x0[b,v,f]^2)
// out[b,i,j] = (sum_f x0[b,i,f]*x0[b,j,f]) / (n[i]*n[j])

#define BATCH 64
#define VDIM 512
#define FDIM 512
#define XBS (2 * VDIM * FDIM)      // x batch stride in floats (T=2)
#define OBS (VDIM * VDIM)          // out batch stride in floats

typedef __bf16 bf16x8 __attribute__((ext_vector_type(8)));
typedef __bf16 bf16x4 __attribute__((ext_vector_type(4)));
typedef float f32x4 __attribute__((ext_vector_type(4)));

#define BM 128
#define BK 64                      // bf16 elems per K-step

// ws layout: [0, 33554432): bf16 x0 copy (64*512*512); then f32 nsq[512]
#define NSQ_OFF 33554432

// global -> LDS direct copy, 16B per lane (dest is wave-uniform base + lane*16)
#define GLL16(g, l)                                                          \
    __builtin_amdgcn_global_load_lds(                                        \
        (const __attribute__((address_space(1))) void*)(g),                  \
        (__attribute__((address_space(3))) void*)(l), 16, 0, 0)

// ---------------- cvt+norm kernel: batch-major, XCD-aligned with gram ----------------
// 1024 blocks x 256 threads. Block (b, g) converts a contiguous 32-row slab of
// batch b (64 KB read, 32 KB ws write) on the SAME XCD that gram will use for
// batch b -> ws stays dirty-resident in that XCD's L2 (8 batches x 512 KB = 4 MB).
__global__ __launch_bounds__(256) void cvt_norm_kernel(const float* __restrict__ x,
                                                       __bf16* __restrict__ xb,
                                                       float* __restrict__ nsq) {
    const int bid = blockIdx.x;
    const int L = (bid & 7) * 128 + (bid >> 3);   // chunked XCD map (1024 % 8 == 0)
    const int b = L >> 4;         // batch
    const int g = L & 15;         // 32-row group
    const int tid = threadIdx.x;
    const int r = tid >> 3;       // 0..31 local row (8 threads per row)
    const int seg = tid & 7;      // 0..7

    const f32x4* src = (const f32x4*)(x + (size_t)b * XBS + (size_t)(g * 32) * FDIM);
    bf16x4* dst = (bf16x4*)(xb + (size_t)b * (VDIM * FDIM) + (size_t)(g * 32) * FDIM);

    float s = 0.f;
    #pragma unroll
    for (int k = 0; k < 16; ++k) {
        int c = r * 128 + seg + k * 8;   // f32x4 index within slab (row r, 128/row)
        f32x4 d = src[c];
        s += d[0] * d[0] + d[1] * d[1] + d[2] * d[2] + d[3] * d[3];
        bf16x4 p;
        p[0] = (__bf16)d[0]; p[1] = (__bf16)d[1]; p[2] = (__bf16)d[2]; p[3] = (__bf16)d[3];
        dst[c] = p;
    }
    // 8 consecutive lanes share a row -> 3-step xor reduce
    s += __shfl_xor(s, 1, 64);
    s += __shfl_xor(s, 2, 64);
    s += __shfl_xor(s, 4, 64);
    __shared__ float nl[32];
    if (seg == 0) nl[r] = s;
    __syncthreads();
    if (tid < 32) atomicAdd(&nsq[g * 32 + tid], nl[tid]);   // device-scope
}

// ---------------- gram kernel: bf16 global_load_lds + swizzled LDS (R2 structure) ----------------
__global__ __launch_bounds__(256) void gram_kernel(const __bf16* __restrict__ xb,
                                                   const float* __restrict__ nsq,
                                                   float* __restrict__ out) {
    __shared__ __bf16 As[BM * BK];   // 16 KB, linear [128][64] (+XOR swizzle via src)
    __shared__ __bf16 Bs[BM * BK];

    // 64 batches x 16 tiles = 1024 blocks
    // XCD chunked swizzle: 1024 / 8 = 128 contiguous logical wgs per XCD (8 batches)
    const int bid = blockIdx.x;
    const int wg = (bid & 7) * 128 + (bid >> 3);
    const int batch = wg >> 4;
    const int tile = wg & 15;
    const int ti = tile >> 2;
    const int tj = tile & 3;

    const __bf16* xbb = xb + (size_t)batch * (VDIM * FDIM);
    const int tid = threadIdx.x;
    const int lane = tid & 63;
    const int wave = tid >> 6;     // 0..3
    const int wr = wave >> 1;      // 0..1
    const int wc = wave & 1;       // 0..1

    // ---- staging addresses (constant per thread; only kk advances) ----
    // chunk c = it*256 + tid in [0,1024): row = c>>3, cc = c&7
    // LDS chunk (row,cc) holds global 16B-chunk (row, cc ^ (row&7))  [both-sides XOR]
    const __bf16* gA[4];
    const __bf16* gB[4];
    __bf16* la[4];
    __bf16* lb[4];
    #pragma unroll
    for (int it = 0; it < 4; ++it) {
        int c = it * 256 + tid;
        int row = c >> 3;
        int cs = (c & 7) ^ (row & 7);
        gA[it] = xbb + (size_t)(ti * BM + row) * FDIM + cs * 8;
        gB[it] = xbb + (size_t)(tj * BM + row) * FDIM + cs * 8;
        la[it] = &As[c * 8];
        lb[it] = &Bs[c * 8];
    }

    // ---- fragment LDS byte offsets (constant per lane) ----
    // element (r, k=ks*32+(lane>>4)*8) lives at LDS chunk (r, (ks*4+(lane>>4)) ^ (r&7))
    int offA[2][4], offB[2][4];
    #pragma unroll
    for (int ks = 0; ks < 2; ++ks) {
        #pragma unroll
        for (int m = 0; m < 4; ++m) {
            int rA = wr * 64 + m * 16 + (lane & 15);
            int rB = wc * 64 + m * 16 + (lane & 15);
            int gch = ks * 4 + (lane >> 4);
            offA[ks][m] = rA * (BK * 2) + ((gch ^ (rA & 7)) * 16);
            offB[ks][m] = rB * (BK * 2) + ((gch ^ (rB & 7)) * 16);
        }
    }

    f32x4 acc[4][4];
    #pragma unroll
    for (int m = 0; m < 4; ++m)
        #pragma unroll
        for (int n = 0; n < 4; ++n)
            acc[m][n] = (f32x4){0.f, 0.f, 0.f, 0.f};

    for (int kk = 0; kk < FDIM; kk += BK) {
        #pragma unroll
        for (int it = 0; it < 4; ++it) {
            GLL16(gA[it] + kk, la[it]);
            GLL16(gB[it] + kk, lb[it]);
        }
        __syncthreads();

        #pragma unroll
        for (int ks = 0; ks < 2; ++ks) {
            bf16x8 af[4], bfr[4];
            #pragma unroll
            for (int m = 0; m < 4; ++m) {
                af[m]  = *(const bf16x8*)((const char*)As + offA[ks][m]);
                bfr[m] = *(const bf16x8*)((const char*)Bs + offB[ks][m]);
            }
            #pragma unroll
            for (int m = 0; m < 4; ++m)
                #pragma unroll
                for (int n = 0; n < 4; ++n)
                    acc[m][n] = __builtin_amdgcn_mfma_f32_16x16x32_bf16(af[m], bfr[n], acc[m][n], 0, 0, 0);
        }
        __syncthreads();
    }

    // ---- epilogue: scale by rsqrt(nsq[i])*rsqrt(nsq[j]), store ----
    const int rowbase = ti * BM + wr * 64;
    const int colbase = tj * BM + wc * 64;
    float* ob = out + (size_t)batch * OBS;

    float si[16];
    #pragma unroll
    for (int m = 0; m < 4; ++m)
        #pragma unroll
        for (int q = 0; q < 4; ++q)
            si[m * 4 + q] = rsqrtf(nsq[rowbase + m * 16 + (lane >> 4) * 4 + q]);

    #pragma unroll
    for (int n = 0; n < 4; ++n) {
        int j = colbase + n * 16 + (lane & 15);
        float sj = rsqrtf(nsq[j]);
        #pragma unroll
        for (int m = 0; m < 4; ++m) {
            #pragma unroll
            for (int q = 0; q < 4; ++q) {
                int i = rowbase + m * 16 + (lane >> 4) * 4 + q;
                ob[(size_t)i * VDIM + j] = acc[m][n][q] * si[m * 4 + q] * sj;
            }
        }
    }
}

extern "C" void kernel_launch(void* const* d_in, const int* in_sizes, int n_in,
                              void* d_out, int out_size, void* d_ws, size_t ws_size,
                              hipStream_t stream) {
    const float* x = (const float*)d_in[0];
    float* out = (float*)d_out;
    __bf16* xbf = (__bf16*)d_ws;
    float* nsq = (float*)((char*)d_ws + NSQ_OFF);

    // nsq accumulates via atomics; zero it deterministically each launch
    hipMemsetAsync(nsq, 0, VDIM * sizeof(float), stream);
    cvt_norm_kernel<<<BATCH * 16, 256, 0, stream>>>(x, xbf, nsq);
    gram_kernel<<<BATCH * 16, 256, 0, stream>>>(xbf, nsq, out);
}